// Round 6
// baseline (50.626 us; speedup 1.0000x reference)
//
#include <hip/hip_runtime.h>
#include <math.h>

#define DDIM 512
#define THREADS 256
#define BT 128          // block tile (M and N)
#define BK 64           // K-step (one staged LDS tile)
#define NT 32           // N / BT tile grid dimension
#define NTILES (NT * (NT + 1) / 2)   // 528 triangular tiles (divisible by 8)
#define NCH 64          // 64-wide column chunks for partials

typedef __attribute__((ext_vector_type(8))) __bf16 bf16x8;
typedef __attribute__((ext_vector_type(4))) float f32x4;
typedef __attribute__((ext_vector_type(8))) unsigned short ushort8;

__device__ __forceinline__ float bf2f(unsigned short u) {
  union { unsigned int i; float f; } v; v.i = ((unsigned int)u) << 16; return v.f;
}
__device__ __forceinline__ unsigned short f2bf(float f) {
  unsigned int u = __builtin_bit_cast(unsigned int, f);
  return (unsigned short)((u + 0x7fffu + ((u >> 16) & 1u)) >> 16);
}

#define GLOAD_LDS16(gp, lp)                                                   \
  __builtin_amdgcn_global_load_lds(                                           \
      (const __attribute__((address_space(1))) unsigned int*)(gp),            \
      (__attribute__((address_space(3))) unsigned int*)(lp), 16, 0, 0)

// ---- kernel 1: normalize rows w and w+B to bf16, compute pos[w]=dot/temp ----
__global__ void k_prep(const float* __restrict__ zi, const float* __restrict__ zj,
                       const float* __restrict__ tempp,
                       unsigned short* __restrict__ znb, float* __restrict__ pos,
                       int B) {
  int wv = (blockIdx.x * blockDim.x + threadIdx.x) >> 6;
  int lane = threadIdx.x & 63;
  if (wv >= B) return;
  const float* a = zi + (size_t)wv * DDIM;
  const float* b = zj + (size_t)wv * DDIM;
  float4 a0 = *(const float4*)(a + lane * 8);
  float4 a1 = *(const float4*)(a + lane * 8 + 4);
  float4 b0 = *(const float4*)(b + lane * 8);
  float4 b1 = *(const float4*)(b + lane * 8 + 4);
  float av[8] = {a0.x, a0.y, a0.z, a0.w, a1.x, a1.y, a1.z, a1.w};
  float bv[8] = {b0.x, b0.y, b0.z, b0.w, b1.x, b1.y, b1.z, b1.w};
  float sa = 0.f, sb = 0.f;
#pragma unroll
  for (int i = 0; i < 8; ++i) { sa = fmaf(av[i], av[i], sa); sb = fmaf(bv[i], bv[i], sb); }
#pragma unroll
  for (int off = 32; off; off >>= 1) { sa += __shfl_xor(sa, off, 64); sb += __shfl_xor(sb, off, 64); }
  float ia = 1.f / fmaxf(sqrtf(sa), 1e-8f);
  float ib = 1.f / fmaxf(sqrtf(sb), 1e-8f);
  ushort8 ua, ub;
  float fa[8], fb[8];
#pragma unroll
  for (int i = 0; i < 8; ++i) {
    unsigned short x = f2bf(av[i] * ia); ua[i] = x; fa[i] = bf2f(x);
    unsigned short y = f2bf(bv[i] * ib); ub[i] = y; fb[i] = bf2f(y);
  }
  *(ushort8*)(znb + (size_t)wv * DDIM + lane * 8) = ua;
  *(ushort8*)(znb + (size_t)(wv + B) * DDIM + lane * 8) = ub;
  float pd = 0.f;
#pragma unroll
  for (int i = 0; i < 8; ++i) pd = fmaf(fa[i], fb[i], pd);
#pragma unroll
  for (int off = 32; off; off >>= 1) pd += __shfl_xor(pd, off, 64);
  if (lane == 0) {
    float p = pd / tempp[0];
    pos[wv] = p; pos[wv + B] = p;
  }
}

// stage one 128x64 bf16 panel into LDS (linear dest, swizzled global source)
__device__ __forceinline__ void stage_tile(const unsigned short* __restrict__ znb,
                                           int panel0, int k0, unsigned char* dst,
                                           int wave, int lane) {
  const int srow_in = lane >> 3;                  // 0..7 within 8-row region
  const int slog = (lane & 7) ^ srow_in;          // logical 16B k-slot (involution)
#pragma unroll
  for (int j = 0; j < 4; ++j) {
    const int ww = wave * 4 + j;                  // region 0..15
    const int row = 8 * ww + srow_in;
    GLOAD_LDS16(znb + (size_t)(panel0 + row) * DDIM + k0 + slog * 8, dst + ww * 1024);
  }
}

// ---- kernel 2: symmetric MFMA Gram tiles, single-buffer LDS (32 KB) --------
__global__ __launch_bounds__(THREADS, 4) void k_main(
    const unsigned short* __restrict__ znb, const float* __restrict__ pos,
    const float* __restrict__ tempp, float* __restrict__ partS,
    float* __restrict__ partC, int B) {
  // XCD-aware bijective swizzle (528 = 8 * 66): same-bi blocks share an XCD L2
  int tri = (blockIdx.x & 7) * (NTILES / 8) + (blockIdx.x >> 3);
  // decode upper-triangular tile (bi <= bj)
  int bi = 0;
  while (tri >= NT - bi) { tri -= NT - bi; ++bi; }
  const int bj = bi + tri;
  const int r0 = bi * BT, c0 = bj * BT;
  const bool diag = (bi == bj);
  const float invt = 1.0f / tempp[0];

  __shared__ __align__(16) unsigned char sA[BT * BK * 2];  // 16 KB
  __shared__ __align__(16) unsigned char sB[BT * BK * 2];  // 16 KB

  const int t = threadIdx.x;
  const int lane = t & 63;
  const int wave = t >> 6;
  const int wr = wave >> 1, wc = wave & 1;   // 2x2 wave grid, each 64x64
  const int cl = lane & 15, g = lane >> 4;

  f32x4 acc[4][4];
#pragma unroll
  for (int m = 0; m < 4; ++m)
#pragma unroll
    for (int n = 0; n < 4; ++n) acc[m][n] = (f32x4){0.f, 0.f, 0.f, 0.f};

  for (int kt = 0; kt < DDIM / BK; ++kt) {   // 8 K-tiles, single buffer
    stage_tile(znb, r0, kt * BK, sA, wave, lane);
    if (!diag) stage_tile(znb, c0, kt * BK, sB, wave, lane);
    __syncthreads();                          // drains DMA, LDS ready

    const unsigned char* pA = sA;
    const unsigned char* pB = diag ? sA : sB;
#pragma unroll
    for (int ks = 0; ks < 2; ++ks) {
      const int phys = (g + ks * 4) ^ (cl & 7);
      bf16x8 aF[4], bF[4];
#pragma unroll
      for (int m = 0; m < 4; ++m)
        aF[m] = *(const bf16x8*)(pA + (wr * 64 + m * 16 + cl) * 128 + phys * 16);
#pragma unroll
      for (int n = 0; n < 4; ++n)
        bF[n] = *(const bf16x8*)(pB + (wc * 64 + n * 16 + cl) * 128 + phys * 16);
#pragma unroll
      for (int m = 0; m < 4; ++m)
#pragma unroll
        for (int n = 0; n < 4; ++n)
          acc[m][n] = __builtin_amdgcn_mfma_f32_16x16x32_bf16(aF[m], bF[n], acc[m][n], 0, 0, 0);
    }
    if (kt + 1 < DDIM / BK)
      __syncthreads();                        // reads done before next overwrite
  }

  // ---- epilogue: row partials (always) + col partials (off-diag tiles) ----
  int growv[16], gpartr[16];
  float pvr[16];
#pragma unroll
  for (int m = 0; m < 4; ++m)
#pragma unroll
    for (int reg = 0; reg < 4; ++reg) {
      int idx = m * 4 + reg;
      int grow = r0 + wr * 64 + m * 16 + g * 4 + reg;
      growv[idx] = grow;
      gpartr[idx] = (grow < B) ? grow + B : grow - B;
      pvr[idx] = pos[grow];
    }
  int gcolv[4], gpartc[4];
  float pvc[4];
#pragma unroll
  for (int n = 0; n < 4; ++n) {
    int gcol = c0 + wc * 64 + n * 16 + cl;
    gcolv[n] = gcol;
    gpartc[n] = (gcol < B) ? gcol + B : gcol - B;
    pvc[n] = pos[gcol];
  }

  float ssr[16], ccr[16], ssc[4], ccc[4];
#pragma unroll
  for (int i = 0; i < 16; ++i) { ssr[i] = 0.f; ccr[i] = 0.f; }
#pragma unroll
  for (int n = 0; n < 4; ++n) { ssc[n] = 0.f; ccc[n] = 0.f; }

#pragma unroll
  for (int m = 0; m < 4; ++m)
#pragma unroll
    for (int n = 0; n < 4; ++n)
#pragma unroll
      for (int reg = 0; reg < 4; ++reg) {
        const int idx = m * 4 + reg;
        float val = acc[m][n][reg] * invt;
        float e = __expf(val);
        bool isd = diag && (gcolv[n] == growv[idx]);
        if (!isd) {
          ssr[idx] += e;
          ccr[idx] += (gcolv[n] != gpartr[idx] && val > pvr[idx]) ? 1.f : 0.f;
        }
        if (!diag) {
          ssc[n] += e;
          ccc[n] += (growv[idx] != gpartc[n] && val > pvc[n]) ? 1.f : 0.f;
        }
      }

  // row partials: reduce over cl (16 lanes), write chunk 2*bj + wc
  const int chR = bj * 2 + wc;
#pragma unroll
  for (int idx = 0; idx < 16; ++idx) {
    float s = ssr[idx], c = ccr[idx];
#pragma unroll
    for (int off = 1; off < 16; off <<= 1) {
      s += __shfl_xor(s, off, 64);
      c += __shfl_xor(c, off, 64);
    }
    if (cl == 0) {
      partS[(size_t)growv[idx] * NCH + chR] = s;
      partC[(size_t)growv[idx] * NCH + chR] = c;
    }
  }
  // col partials: reduce over g (xor 16,32), write chunk 2*bi + wr
  if (!diag) {
    const int chC = bi * 2 + wr;
#pragma unroll
    for (int n = 0; n < 4; ++n) {
      float s = ssc[n], c = ccc[n];
      s += __shfl_xor(s, 16, 64); c += __shfl_xor(c, 16, 64);
      s += __shfl_xor(s, 32, 64); c += __shfl_xor(c, 32, 64);
      if (g == 0) {
        partS[(size_t)gcolv[n] * NCH + chC] = s;
        partC[(size_t)gcolv[n] * NCH + chC] = c;
      }
    }
  }
}

// ---- kernel 3: per-row combine of 64 chunks -> rowLoss, rowCnt ----
__global__ void k_rowfin(const float* __restrict__ partS, const float* __restrict__ partC,
                         const float* __restrict__ pos, float* __restrict__ rowL,
                         float* __restrict__ rowC, int N) {
  int r = (blockIdx.x * blockDim.x + threadIdx.x) >> 6;
  int lane = threadIdx.x & 63;
  if (r >= N) return;
  float s = partS[(size_t)r * NCH + lane];
  float c = partC[(size_t)r * NCH + lane];
#pragma unroll
  for (int off = 32; off; off >>= 1) { s += __shfl_xor(s, off, 64); c += __shfl_xor(c, off, 64); }
  if (lane == 0) {
    rowL[r] = logf(s) - pos[r];
    rowC[r] = c;
  }
}

// ---- kernel 4: final reduction to (loss, avg_rank) ----
__global__ void k_final(const float* __restrict__ rowL, const float* __restrict__ rowC,
                        float* __restrict__ out, int N) {
  float ls = 0.f, cs = 0.f;
  for (int r = threadIdx.x; r < N; r += THREADS) { ls += rowL[r]; cs += rowC[r]; }
  __shared__ float l[THREADS], c[THREADS];
  l[threadIdx.x] = ls; c[threadIdx.x] = cs;
  __syncthreads();
  for (int off = THREADS / 2; off; off >>= 1) {
    if (threadIdx.x < off) { l[threadIdx.x] += l[threadIdx.x + off]; c[threadIdx.x] += c[threadIdx.x + off]; }
    __syncthreads();
  }
  if (threadIdx.x == 0) { out[0] = l[0] / (float)N; out[1] = c[0] / (float)N; }
}

extern "C" void kernel_launch(void* const* d_in, const int* in_sizes, int n_in,
                              void* d_out, int out_size, void* d_ws, size_t ws_size,
                              hipStream_t stream) {
  const float* zi = (const float*)d_in[0];
  const float* zj = (const float*)d_in[1];
  const float* temp = (const float*)d_in[2];
  float* out = (float*)d_out;

  const int B = in_sizes[0] / DDIM;   // 2048
  const int N = 2 * B;                // 4096

  unsigned short* znb = (unsigned short*)d_ws;          // N*DDIM bf16 = 4 MB
  float* fws = (float*)(znb + (size_t)N * DDIM);
  float* pos   = fws;                                    // N
  float* partS = pos + N;                                // N*NCH = 1 MB
  float* partC = partS + (size_t)N * NCH;                // N*NCH = 1 MB
  float* rowL  = partC + (size_t)N * NCH;                // N
  float* rowC  = rowL + N;                               // N

  k_prep<<<(B * 64) / THREADS, THREADS, 0, stream>>>(zi, zj, temp, znb, pos, B);
  k_main<<<NTILES, THREADS, 0, stream>>>(znb, pos, temp, partS, partC, B);
  k_rowfin<<<(N * 64) / THREADS, THREADS, 0, stream>>>(partS, partC, pos, rowL, rowC, N);
  k_final<<<1, THREADS, 0, stream>>>(rowL, rowC, out, N);
}

// Round 7
// 47.184 us; speedup vs baseline: 1.0729x; 1.0729x over previous
//
#include <hip/hip_runtime.h>
#include <math.h>

#define DDIM 512
#define THREADS 256
#define BT 128          // block tile (M and N)
#define BK 128          // K-step (one staged LDS tile) -> only 4 stage events
#define NT 32           // N / BT tile grid dimension
#define NTILES (NT * (NT + 1) / 2)   // 528 triangular tiles (divisible by 8)
#define NCH 64          // 64-wide column chunks for partials

typedef __attribute__((ext_vector_type(8))) __bf16 bf16x8;
typedef __attribute__((ext_vector_type(4))) float f32x4;
typedef __attribute__((ext_vector_type(8))) unsigned short ushort8;

__device__ __forceinline__ float bf2f(unsigned short u) {
  union { unsigned int i; float f; } v; v.i = ((unsigned int)u) << 16; return v.f;
}
__device__ __forceinline__ unsigned short f2bf(float f) {
  unsigned int u = __builtin_bit_cast(unsigned int, f);
  return (unsigned short)((u + 0x7fffu + ((u >> 16) & 1u)) >> 16);
}

#define GLOAD_LDS16(gp, lp)                                                   \
  __builtin_amdgcn_global_load_lds(                                           \
      (const __attribute__((address_space(1))) unsigned int*)(gp),            \
      (__attribute__((address_space(3))) unsigned int*)(lp), 16, 0, 0)

// ---- kernel 1: normalize rows w and w+B to bf16, compute pos[w]=dot/temp ----
__global__ void k_prep(const float* __restrict__ zi, const float* __restrict__ zj,
                       const float* __restrict__ tempp,
                       unsigned short* __restrict__ znb, float* __restrict__ pos,
                       int B) {
  int wv = (blockIdx.x * blockDim.x + threadIdx.x) >> 6;
  int lane = threadIdx.x & 63;
  if (wv >= B) return;
  const float* a = zi + (size_t)wv * DDIM;
  const float* b = zj + (size_t)wv * DDIM;
  float4 a0 = *(const float4*)(a + lane * 8);
  float4 a1 = *(const float4*)(a + lane * 8 + 4);
  float4 b0 = *(const float4*)(b + lane * 8);
  float4 b1 = *(const float4*)(b + lane * 8 + 4);
  float av[8] = {a0.x, a0.y, a0.z, a0.w, a1.x, a1.y, a1.z, a1.w};
  float bv[8] = {b0.x, b0.y, b0.z, b0.w, b1.x, b1.y, b1.z, b1.w};
  float sa = 0.f, sb = 0.f;
#pragma unroll
  for (int i = 0; i < 8; ++i) { sa = fmaf(av[i], av[i], sa); sb = fmaf(bv[i], bv[i], sb); }
#pragma unroll
  for (int off = 32; off; off >>= 1) { sa += __shfl_xor(sa, off, 64); sb += __shfl_xor(sb, off, 64); }
  float ia = 1.f / fmaxf(sqrtf(sa), 1e-8f);
  float ib = 1.f / fmaxf(sqrtf(sb), 1e-8f);
  ushort8 ua, ub;
  float fa[8], fb[8];
#pragma unroll
  for (int i = 0; i < 8; ++i) {
    unsigned short x = f2bf(av[i] * ia); ua[i] = x; fa[i] = bf2f(x);
    unsigned short y = f2bf(bv[i] * ib); ub[i] = y; fb[i] = bf2f(y);
  }
  *(ushort8*)(znb + (size_t)wv * DDIM + lane * 8) = ua;
  *(ushort8*)(znb + (size_t)(wv + B) * DDIM + lane * 8) = ub;
  float pd = 0.f;
#pragma unroll
  for (int i = 0; i < 8; ++i) pd = fmaf(fa[i], fb[i], pd);
#pragma unroll
  for (int off = 32; off; off >>= 1) pd += __shfl_xor(pd, off, 64);
  if (lane == 0) {
    float p = pd / tempp[0];
    pos[wv] = p; pos[wv + B] = p;
  }
}

// stage one 128x128 bf16 panel into LDS (linear dest, swizzled global source)
// region = 4 rows x 16 slots (1 KB); 32 regions; 8 per wave
__device__ __forceinline__ void stage_tile(const unsigned short* __restrict__ znb,
                                           int panel0, int k0, unsigned char* dst,
                                           int wave, int lane) {
  const int row_in = lane >> 4;                   // 0..3 within 4-row region
  const int sphys = lane & 15;                    // physical 16B slot in row
#pragma unroll
  for (int j = 0; j < 8; ++j) {
    const int ww = wave * 8 + j;                  // region 0..31
    const int row = 4 * ww + row_in;
    const int slog = sphys ^ (row & 7);           // logical k-slot (involution)
    GLOAD_LDS16(znb + (size_t)(panel0 + row) * DDIM + k0 + slog * 8, dst + ww * 1024);
  }
}

// ---- kernel 2: symmetric MFMA Gram tiles, single-buffer BK=128 -------------
__global__ __launch_bounds__(THREADS) void k_main(
    const unsigned short* __restrict__ znb, const float* __restrict__ pos,
    const float* __restrict__ tempp, float* __restrict__ partS,
    float* __restrict__ partC, int B) {
  // XCD-aware bijective swizzle (528 = 8 * 66): same-bi blocks share an XCD L2
  int tri = (blockIdx.x & 7) * (NTILES / 8) + (blockIdx.x >> 3);
  // decode upper-triangular tile (bi <= bj)
  int bi = 0;
  while (tri >= NT - bi) { tri -= NT - bi; ++bi; }
  const int bj = bi + tri;
  const int r0 = bi * BT, c0 = bj * BT;
  const bool diag = (bi == bj);
  const float invt = 1.0f / tempp[0];

  __shared__ __align__(16) unsigned char sA[BT * BK * 2];  // 32 KB
  __shared__ __align__(16) unsigned char sB[BT * BK * 2];  // 32 KB

  const int t = threadIdx.x;
  const int lane = t & 63;
  const int wave = t >> 6;
  const int wr = wave >> 1, wc = wave & 1;   // 2x2 wave grid, each 64x64
  const int cl = lane & 15, g = lane >> 4;

  f32x4 acc[4][4];
#pragma unroll
  for (int m = 0; m < 4; ++m)
#pragma unroll
    for (int n = 0; n < 4; ++n) acc[m][n] = (f32x4){0.f, 0.f, 0.f, 0.f};

  for (int kt = 0; kt < DDIM / BK; ++kt) {   // 4 K-tiles, single buffer
    stage_tile(znb, r0, kt * BK, sA, wave, lane);
    if (!diag) stage_tile(znb, c0, kt * BK, sB, wave, lane);
    __syncthreads();                          // drains DMA, LDS ready

    const unsigned char* pA = sA;
    const unsigned char* pB = diag ? sA : sB;
#pragma unroll
    for (int ks = 0; ks < 4; ++ks) {          // 4 k-slices of 32 within BK
      const int phys = (ks * 4 + g) ^ (cl & 7);
      bf16x8 aF[4], bF[4];
#pragma unroll
      for (int m = 0; m < 4; ++m)
        aF[m] = *(const bf16x8*)(pA + (wr * 64 + m * 16 + cl) * 256 + phys * 16);
#pragma unroll
      for (int n = 0; n < 4; ++n)
        bF[n] = *(const bf16x8*)(pB + (wc * 64 + n * 16 + cl) * 256 + phys * 16);
#pragma unroll
      for (int m = 0; m < 4; ++m)
#pragma unroll
        for (int n = 0; n < 4; ++n)
          acc[m][n] = __builtin_amdgcn_mfma_f32_16x16x32_bf16(aF[m], bF[n], acc[m][n], 0, 0, 0);
    }
    if (kt + 1 < DDIM / BK)
      __syncthreads();                        // reads done before next overwrite
  }

  // ---- epilogue: row partials (always) + col partials (off-diag tiles) ----
  int growv[16], gpartr[16];
  float pvr[16];
#pragma unroll
  for (int m = 0; m < 4; ++m)
#pragma unroll
    for (int reg = 0; reg < 4; ++reg) {
      int idx = m * 4 + reg;
      int grow = r0 + wr * 64 + m * 16 + g * 4 + reg;
      growv[idx] = grow;
      gpartr[idx] = (grow < B) ? grow + B : grow - B;
      pvr[idx] = pos[grow];
    }
  int gcolv[4], gpartc[4];
  float pvc[4];
#pragma unroll
  for (int n = 0; n < 4; ++n) {
    int gcol = c0 + wc * 64 + n * 16 + cl;
    gcolv[n] = gcol;
    gpartc[n] = (gcol < B) ? gcol + B : gcol - B;
    pvc[n] = pos[gcol];
  }

  float ssr[16], ccr[16], ssc[4], ccc[4];
#pragma unroll
  for (int i = 0; i < 16; ++i) { ssr[i] = 0.f; ccr[i] = 0.f; }
#pragma unroll
  for (int n = 0; n < 4; ++n) { ssc[n] = 0.f; ccc[n] = 0.f; }

#pragma unroll
  for (int m = 0; m < 4; ++m)
#pragma unroll
    for (int n = 0; n < 4; ++n)
#pragma unroll
      for (int reg = 0; reg < 4; ++reg) {
        const int idx = m * 4 + reg;
        float val = acc[m][n][reg] * invt;
        float e = __expf(val);
        bool isd = diag && (gcolv[n] == growv[idx]);
        if (!isd) {
          ssr[idx] += e;
          ccr[idx] += (gcolv[n] != gpartr[idx] && val > pvr[idx]) ? 1.f : 0.f;
        }
        if (!diag) {
          ssc[n] += e;
          ccc[n] += (growv[idx] != gpartc[n] && val > pvc[n]) ? 1.f : 0.f;
        }
      }

  // row partials: reduce over cl (16 lanes), write chunk 2*bj + wc
  const int chR = bj * 2 + wc;
#pragma unroll
  for (int idx = 0; idx < 16; ++idx) {
    float s = ssr[idx], c = ccr[idx];
#pragma unroll
    for (int off = 1; off < 16; off <<= 1) {
      s += __shfl_xor(s, off, 64);
      c += __shfl_xor(c, off, 64);
    }
    if (cl == 0) {
      partS[(size_t)growv[idx] * NCH + chR] = s;
      partC[(size_t)growv[idx] * NCH + chR] = c;
    }
  }
  // col partials: reduce over g (xor 16,32), write chunk 2*bi + wr
  if (!diag) {
    const int chC = bi * 2 + wr;
#pragma unroll
    for (int n = 0; n < 4; ++n) {
      float s = ssc[n], c = ccc[n];
      s += __shfl_xor(s, 16, 64); c += __shfl_xor(c, 16, 64);
      s += __shfl_xor(s, 32, 64); c += __shfl_xor(c, 32, 64);
      if (g == 0) {
        partS[(size_t)gcolv[n] * NCH + chC] = s;
        partC[(size_t)gcolv[n] * NCH + chC] = c;
      }
    }
  }
}

// ---- kernel 3: per-row combine of 64 chunks -> rowLoss, rowCnt ----
__global__ void k_rowfin(const float* __restrict__ partS, const float* __restrict__ partC,
                         const float* __restrict__ pos, float* __restrict__ rowL,
                         float* __restrict__ rowC, int N) {
  int r = (blockIdx.x * blockDim.x + threadIdx.x) >> 6;
  int lane = threadIdx.x & 63;
  if (r >= N) return;
  float s = partS[(size_t)r * NCH + lane];
  float c = partC[(size_t)r * NCH + lane];
#pragma unroll
  for (int off = 32; off; off >>= 1) { s += __shfl_xor(s, off, 64); c += __shfl_xor(c, off, 64); }
  if (lane == 0) {
    rowL[r] = logf(s) - pos[r];
    rowC[r] = c;
  }
}

// ---- kernel 4: final reduction to (loss, avg_rank) ----
__global__ void k_final(const float* __restrict__ rowL, const float* __restrict__ rowC,
                        float* __restrict__ out, int N) {
  float ls = 0.f, cs = 0.f;
  for (int r = threadIdx.x; r < N; r += THREADS) { ls += rowL[r]; cs += rowC[r]; }
  __shared__ float l[THREADS], c[THREADS];
  l[threadIdx.x] = ls; c[threadIdx.x] = cs;
  __syncthreads();
  for (int off = THREADS / 2; off; off >>= 1) {
    if (threadIdx.x < off) { l[threadIdx.x] += l[threadIdx.x + off]; c[threadIdx.x] += c[threadIdx.x + off]; }
    __syncthreads();
  }
  if (threadIdx.x == 0) { out[0] = l[0] / (float)N; out[1] = c[0] / (float)N; }
}

extern "C" void kernel_launch(void* const* d_in, const int* in_sizes, int n_in,
                              void* d_out, int out_size, void* d_ws, size_t ws_size,
                              hipStream_t stream) {
  const float* zi = (const float*)d_in[0];
  const float* zj = (const float*)d_in[1];
  const float* temp = (const float*)d_in[2];
  float* out = (float*)d_out;

  const int B = in_sizes[0] / DDIM;   // 2048
  const int N = 2 * B;                // 4096

  unsigned short* znb = (unsigned short*)d_ws;          // N*DDIM bf16 = 4 MB
  float* fws = (float*)(znb + (size_t)N * DDIM);
  float* pos   = fws;                                    // N
  float* partS = pos + N;                                // N*NCH = 1 MB
  float* partC = partS + (size_t)N * NCH;                // N*NCH = 1 MB
  float* rowL  = partC + (size_t)N * NCH;                // N
  float* rowC  = rowL + N;                               // N

  k_prep<<<(B * 64) / THREADS, THREADS, 0, stream>>>(zi, zj, temp, znb, pos, B);
  k_main<<<NTILES, THREADS, 0, stream>>>(znb, pos, temp, partS, partC, B);
  k_rowfin<<<(N * 64) / THREADS, THREADS, 0, stream>>>(partS, partC, pos, rowL, rowC, N);
  k_final<<<1, THREADS, 0, stream>>>(rowL, rowC, out, N);
}

// Round 8
// 43.103 us; speedup vs baseline: 1.1745x; 1.0947x over previous
//
#include <hip/hip_runtime.h>
#include <math.h>

#define DDIM 512
#define THREADS 256
#define BT 64           // block tile (M and N)
#define BK 64           // K-step (one staged LDS tile)
#define NT 64           // N / BT tile grid dimension
#define NTILES (NT * (NT + 1) / 2)   // 2080 triangular tiles (divisible by 8)
#define NCH 64          // 64-wide column chunks for partials

typedef __attribute__((ext_vector_type(8))) __bf16 bf16x8;
typedef __attribute__((ext_vector_type(4))) float f32x4;
typedef __attribute__((ext_vector_type(8))) unsigned short ushort8;

__device__ __forceinline__ float bf2f(unsigned short u) {
  union { unsigned int i; float f; } v; v.i = ((unsigned int)u) << 16; return v.f;
}
__device__ __forceinline__ unsigned short f2bf(float f) {
  unsigned int u = __builtin_bit_cast(unsigned int, f);
  return (unsigned short)((u + 0x7fffu + ((u >> 16) & 1u)) >> 16);
}

#define GLOAD_LDS16(gp, lp)                                                   \
  __builtin_amdgcn_global_load_lds(                                           \
      (const __attribute__((address_space(1))) unsigned int*)(gp),            \
      (__attribute__((address_space(3))) unsigned int*)(lp), 16, 0, 0)

// ---- kernel 1: normalize rows w and w+B to bf16, compute pos[w]=dot/temp ----
__global__ void k_prep(const float* __restrict__ zi, const float* __restrict__ zj,
                       const float* __restrict__ tempp,
                       unsigned short* __restrict__ znb, float* __restrict__ pos,
                       int B) {
  int wv = (blockIdx.x * blockDim.x + threadIdx.x) >> 6;
  int lane = threadIdx.x & 63;
  if (wv >= B) return;
  const float* a = zi + (size_t)wv * DDIM;
  const float* b = zj + (size_t)wv * DDIM;
  float4 a0 = *(const float4*)(a + lane * 8);
  float4 a1 = *(const float4*)(a + lane * 8 + 4);
  float4 b0 = *(const float4*)(b + lane * 8);
  float4 b1 = *(const float4*)(b + lane * 8 + 4);
  float av[8] = {a0.x, a0.y, a0.z, a0.w, a1.x, a1.y, a1.z, a1.w};
  float bv[8] = {b0.x, b0.y, b0.z, b0.w, b1.x, b1.y, b1.z, b1.w};
  float sa = 0.f, sb = 0.f;
#pragma unroll
  for (int i = 0; i < 8; ++i) { sa = fmaf(av[i], av[i], sa); sb = fmaf(bv[i], bv[i], sb); }
#pragma unroll
  for (int off = 32; off; off >>= 1) { sa += __shfl_xor(sa, off, 64); sb += __shfl_xor(sb, off, 64); }
  float ia = 1.f / fmaxf(sqrtf(sa), 1e-8f);
  float ib = 1.f / fmaxf(sqrtf(sb), 1e-8f);
  ushort8 ua, ub;
  float fa[8], fb[8];
#pragma unroll
  for (int i = 0; i < 8; ++i) {
    unsigned short x = f2bf(av[i] * ia); ua[i] = x; fa[i] = bf2f(x);
    unsigned short y = f2bf(bv[i] * ib); ub[i] = y; fb[i] = bf2f(y);
  }
  *(ushort8*)(znb + (size_t)wv * DDIM + lane * 8) = ua;
  *(ushort8*)(znb + (size_t)(wv + B) * DDIM + lane * 8) = ub;
  float pd = 0.f;
#pragma unroll
  for (int i = 0; i < 8; ++i) pd = fmaf(fa[i], fb[i], pd);
#pragma unroll
  for (int off = 32; off; off >>= 1) pd += __shfl_xor(pd, off, 64);
  if (lane == 0) {
    float p = pd / tempp[0];
    pos[wv] = p; pos[wv + B] = p;
  }
}

// stage one 64x64 bf16 panel (8 KB) into LDS; 8 regions of 8 rows x 8 slots
__device__ __forceinline__ void stage_tile(const unsigned short* __restrict__ znb,
                                           int panel0, int k0, unsigned char* dst,
                                           int wave, int lane) {
  const int srow_in = lane >> 3;                  // 0..7 within 8-row region
  const int slog = (lane & 7) ^ srow_in;          // logical 16B k-slot (involution)
#pragma unroll
  for (int j = 0; j < 2; ++j) {
    const int ww = wave * 2 + j;                  // region 0..7
    const int row = 8 * ww + srow_in;
    GLOAD_LDS16(znb + (size_t)(panel0 + row) * DDIM + k0 + slog * 8, dst + ww * 1024);
  }
}

// ---- kernel 2: symmetric MFMA Gram tiles, BT=64 for 8 blocks/CU ------------
__global__ __launch_bounds__(THREADS) void k_main(
    const unsigned short* __restrict__ znb, const float* __restrict__ pos,
    const float* __restrict__ tempp, float* __restrict__ partS,
    float* __restrict__ partC, int B) {
  // XCD-aware bijective swizzle (2080 = 8 * 260)
  int tri = (blockIdx.x & 7) * (NTILES / 8) + (blockIdx.x >> 3);
  // decode upper-triangular tile (bi <= bj)
  int bi = 0;
  while (tri >= NT - bi) { tri -= NT - bi; ++bi; }
  const int bj = bi + tri;
  const int r0 = bi * BT, c0 = bj * BT;
  const bool diag = (bi == bj);
  const float invt = 1.0f / tempp[0];

  __shared__ __align__(16) unsigned char sA[BT * BK * 2];  // 8 KB
  __shared__ __align__(16) unsigned char sB[BT * BK * 2];  // 8 KB

  const int t = threadIdx.x;
  const int lane = t & 63;
  const int wave = t >> 6;
  const int wr = wave >> 1, wc = wave & 1;   // 2x2 wave grid, each 32x32
  const int cl = lane & 15, g = lane >> 4;

  f32x4 acc[2][2];
#pragma unroll
  for (int m = 0; m < 2; ++m)
#pragma unroll
    for (int n = 0; n < 2; ++n) acc[m][n] = (f32x4){0.f, 0.f, 0.f, 0.f};

  for (int kt = 0; kt < DDIM / BK; ++kt) {   // 8 K-tiles, single buffer
    stage_tile(znb, r0, kt * BK, sA, wave, lane);
    if (!diag) stage_tile(znb, c0, kt * BK, sB, wave, lane);
    __syncthreads();                          // drains DMA, LDS ready

    const unsigned char* pA = sA;
    const unsigned char* pB = diag ? sA : sB;
#pragma unroll
    for (int ks = 0; ks < 2; ++ks) {
      const int phys = (g + ks * 4) ^ (cl & 7);
      bf16x8 aF[2], bF[2];
#pragma unroll
      for (int m = 0; m < 2; ++m)
        aF[m] = *(const bf16x8*)(pA + (wr * 32 + m * 16 + cl) * 128 + phys * 16);
#pragma unroll
      for (int n = 0; n < 2; ++n)
        bF[n] = *(const bf16x8*)(pB + (wc * 32 + n * 16 + cl) * 128 + phys * 16);
#pragma unroll
      for (int m = 0; m < 2; ++m)
#pragma unroll
        for (int n = 0; n < 2; ++n)
          acc[m][n] = __builtin_amdgcn_mfma_f32_16x16x32_bf16(aF[m], bF[n], acc[m][n], 0, 0, 0);
    }
    __syncthreads();                          // reads done before next overwrite
  }

  // ---- epilogue: fused exp-sum / rank-count, both directions ----
  int growv[8], gpartr[8];
  float pvr[8];
#pragma unroll
  for (int m = 0; m < 2; ++m)
#pragma unroll
    for (int reg = 0; reg < 4; ++reg) {
      int idx = m * 4 + reg;
      int grow = r0 + wr * 32 + m * 16 + g * 4 + reg;
      growv[idx] = grow;
      gpartr[idx] = (grow < B) ? grow + B : grow - B;
      pvr[idx] = pos[grow];
    }
  int gcolv[2], gpartc[2];
  float pvc[2];
#pragma unroll
  for (int n = 0; n < 2; ++n) {
    int gcol = c0 + wc * 32 + n * 16 + cl;
    gcolv[n] = gcol;
    gpartc[n] = (gcol < B) ? gcol + B : gcol - B;
    pvc[n] = pos[gcol];
  }

  float ssr[8], ccr[8], ssc[2], ccc[2];
#pragma unroll
  for (int i = 0; i < 8; ++i) { ssr[i] = 0.f; ccr[i] = 0.f; }
#pragma unroll
  for (int n = 0; n < 2; ++n) { ssc[n] = 0.f; ccc[n] = 0.f; }

#pragma unroll
  for (int m = 0; m < 2; ++m)
#pragma unroll
    for (int n = 0; n < 2; ++n)
#pragma unroll
      for (int reg = 0; reg < 4; ++reg) {
        const int idx = m * 4 + reg;
        float val = acc[m][n][reg] * invt;
        float e = __expf(val);
        bool isd = diag && (gcolv[n] == growv[idx]);
        if (!isd) {
          ssr[idx] += e;
          ccr[idx] += (gcolv[n] != gpartr[idx] && val > pvr[idx]) ? 1.f : 0.f;
        }
        if (!diag) {
          ssc[n] += e;
          ccc[n] += (growv[idx] != gpartc[n] && val > pvc[n]) ? 1.f : 0.f;
        }
      }

  // in-wave reductions: rows over cl (low 4 lane bits), cols over g (bits 4,5)
#pragma unroll
  for (int idx = 0; idx < 8; ++idx) {
#pragma unroll
    for (int off = 1; off < 16; off <<= 1) {
      ssr[idx] += __shfl_xor(ssr[idx], off, 64);
      ccr[idx] += __shfl_xor(ccr[idx], off, 64);
    }
  }
#pragma unroll
  for (int n = 0; n < 2; ++n) {
    ssc[n] += __shfl_xor(ssc[n], 16, 64); ccc[n] += __shfl_xor(ccc[n], 16, 64);
    ssc[n] += __shfl_xor(ssc[n], 32, 64); ccc[n] += __shfl_xor(ccc[n], 32, 64);
  }

  // cross-wave combine via reused LDS: both wc halves sum into one chunk value
  __syncthreads();                            // all frag reads long done; reuse sA
  float* rowSb = (float*)sA;                  // [64 rows][2 wc]
  float* rowCb = rowSb + 128;
  float* colSb = rowSb + 256;                 // [64 cols][2 wr]
  float* colCb = rowSb + 384;
  if (cl == 0) {
#pragma unroll
    for (int m = 0; m < 2; ++m)
#pragma unroll
      for (int reg = 0; reg < 4; ++reg) {
        int idx = m * 4 + reg;
        int r32 = wr * 32 + m * 16 + g * 4 + reg;
        rowSb[r32 * 2 + wc] = ssr[idx];
        rowCb[r32 * 2 + wc] = ccr[idx];
      }
  }
  if (!diag && g == 0) {
#pragma unroll
    for (int n = 0; n < 2; ++n) {
      int c32 = wc * 32 + n * 16 + cl;
      colSb[c32 * 2 + wr] = ssc[n];
      colCb[c32 * 2 + wr] = ccc[n];
    }
  }
  __syncthreads();

  if (wc == 0 && lane < 32) {                 // waves 0,2: write row partials
    int r32 = wr * 32 + lane;
    int r = r0 + r32;
    partS[(size_t)r * NCH + bj] = rowSb[r32 * 2] + rowSb[r32 * 2 + 1];
    partC[(size_t)r * NCH + bj] = rowCb[r32 * 2] + rowCb[r32 * 2 + 1];
  }
  if (!diag && wr == 0 && lane < 32) {        // waves 0,1: write col partials
    int c32 = wc * 32 + lane;
    int c = c0 + c32;
    partS[(size_t)c * NCH + bi] = colSb[c32 * 2] + colSb[c32 * 2 + 1];
    partC[(size_t)c * NCH + bi] = colCb[c32 * 2] + colCb[c32 * 2 + 1];
  }
}

// ---- kernel 3: per-row combine of 64 chunks -> rowLoss, rowCnt ----
__global__ void k_rowfin(const float* __restrict__ partS, const float* __restrict__ partC,
                         const float* __restrict__ pos, float* __restrict__ rowL,
                         float* __restrict__ rowC, int N) {
  int r = (blockIdx.x * blockDim.x + threadIdx.x) >> 6;
  int lane = threadIdx.x & 63;
  if (r >= N) return;
  float s = partS[(size_t)r * NCH + lane];
  float c = partC[(size_t)r * NCH + lane];
#pragma unroll
  for (int off = 32; off; off >>= 1) { s += __shfl_xor(s, off, 64); c += __shfl_xor(c, off, 64); }
  if (lane == 0) {
    rowL[r] = logf(s) - pos[r];
    rowC[r] = c;
  }
}

// ---- kernel 4: final reduction to (loss, avg_rank) ----
__global__ void k_final(const float* __restrict__ rowL, const float* __restrict__ rowC,
                        float* __restrict__ out, int N) {
  float ls = 0.f, cs = 0.f;
  for (int r = threadIdx.x; r < N; r += THREADS) { ls += rowL[r]; cs += rowC[r]; }
  __shared__ float l[THREADS], c[THREADS];
  l[threadIdx.x] = ls; c[threadIdx.x] = cs;
  __syncthreads();
  for (int off = THREADS / 2; off; off >>= 1) {
    if (threadIdx.x < off) { l[threadIdx.x] += l[threadIdx.x + off]; c[threadIdx.x] += c[threadIdx.x + off]; }
    __syncthreads();
  }
  if (threadIdx.x == 0) { out[0] = l[0] / (float)N; out[1] = c[0] / (float)N; }
}

extern "C" void kernel_launch(void* const* d_in, const int* in_sizes, int n_in,
                              void* d_out, int out_size, void* d_ws, size_t ws_size,
                              hipStream_t stream) {
  const float* zi = (const float*)d_in[0];
  const float* zj = (const float*)d_in[1];
  const float* temp = (const float*)d_in[2];
  float* out = (float*)d_out;

  const int B = in_sizes[0] / DDIM;   // 2048
  const int N = 2 * B;                // 4096

  unsigned short* znb = (unsigned short*)d_ws;          // N*DDIM bf16 = 4 MB
  float* fws = (float*)(znb + (size_t)N * DDIM);
  float* pos   = fws;                                    // N
  float* partS = pos + N;                                // N*NCH = 1 MB
  float* partC = partS + (size_t)N * NCH;                // N*NCH = 1 MB
  float* rowL  = partC + (size_t)N * NCH;                // N
  float* rowC  = rowL + N;                               // N

  k_prep<<<(B * 64) / THREADS, THREADS, 0, stream>>>(zi, zj, temp, znb, pos, B);
  k_main<<<NTILES, THREADS, 0, stream>>>(znb, pos, temp, partS, partC, B);
  k_rowfin<<<(N * 64) / THREADS, THREADS, 0, stream>>>(partS, partC, pos, rowL, rowC, N);
  k_final<<<1, THREADS, 0, stream>>>(rowL, rowC, out, N);
}